// Round 1
// baseline (46998.380 us; speedup 1.0000x reference)
//
#include <hip/hip_runtime.h>
#include <math.h>

// Problem constants (fixed by setup_inputs)
static constexpr int Lc = 12;
static constexpr int Hc = 12;
static constexpr int Dc = 768;
static constexpr int DHc = 64;
static constexpr int FFc = 3072;
static constexpr int SENSEc = 64;
static constexpr int ATTc = 64;

static constexpr int BM = 64;
static constexpr int BN = 64;
static constexpr int BK = 16;

// ---------------- block reduction (256 threads = 4 waves) ----------------
__device__ __forceinline__ float blockReduceSum256(float v, float* sred) {
#pragma unroll
    for (int off = 32; off > 0; off >>= 1) v += __shfl_down(v, off, 64);
    int lane = threadIdx.x & 63, wid = threadIdx.x >> 6;
    if (lane == 0) sred[wid] = v;
    __syncthreads();
    float total = sred[0] + sred[1] + sred[2] + sred[3];
    __syncthreads();  // protect sred before next reduction reuses it
    return total;
}

// ---------------- embedding + LayerNorm ----------------
__global__ __launch_bounds__(256) void embed_kernel(
    const int* __restrict__ ids, const int* __restrict__ tts,
    const float* __restrict__ we, const float* __restrict__ pe,
    const float* __restrict__ te, const float* __restrict__ g,
    const float* __restrict__ b, float* __restrict__ x, int S)
{
    int tok = blockIdx.x, t = threadIdx.x;
    int ss = tok % S;
    int id = ids[tok], tt = tts[tok];
    __shared__ float sred[4];
    float v[3];
    float s = 0.f;
#pragma unroll
    for (int i = 0; i < 3; ++i) {
        int d = t + i * 256;
        v[i] = we[(size_t)id * Dc + d] + pe[(size_t)ss * Dc + d] + te[(size_t)tt * Dc + d];
        s += v[i];
    }
    float mu = blockReduceSum256(s, sred) * (1.f / Dc);
    float s2 = 0.f;
#pragma unroll
    for (int i = 0; i < 3; ++i) { v[i] -= mu; s2 += v[i] * v[i]; }
    float rstd = rsqrtf(blockReduceSum256(s2, sred) * (1.f / Dc) + 1e-12f);
    float* xr = x + (size_t)tok * Dc;
#pragma unroll
    for (int i = 0; i < 3; ++i) {
        int d = t + i * 256;
        xr[d] = v[i] * rstd * g[d] + b[d];
    }
}

// ---------------- residual + LayerNorm (in-place on x) ----------------
__global__ __launch_bounds__(256) void resln_kernel(
    float* __restrict__ x, const float* __restrict__ y,
    const float* __restrict__ g, const float* __restrict__ b)
{
    int tok = blockIdx.x, t = threadIdx.x;
    __shared__ float sred[4];
    float* xr = x + (size_t)tok * Dc;
    const float* yr = y + (size_t)tok * Dc;
    float v[3];
    float s = 0.f;
#pragma unroll
    for (int i = 0; i < 3; ++i) {
        int d = t + i * 256;
        v[i] = xr[d] + yr[d];
        s += v[i];
    }
    float mu = blockReduceSum256(s, sred) * (1.f / Dc);
    float s2 = 0.f;
#pragma unroll
    for (int i = 0; i < 3; ++i) { v[i] -= mu; s2 += v[i] * v[i]; }
    float rstd = rsqrtf(blockReduceSum256(s2, sred) * (1.f / Dc) + 1e-12f);
#pragma unroll
    for (int i = 0; i < 3; ++i) {
        int d = t + i * 256;
        xr[d] = v[i] * rstd * g[d] + b[d];
    }
}

// ---------------- fp32 tiled GEMM: C[M,N] = A[M,K] @ W[K,N] + bias (opt GELU) ----------------
__global__ __launch_bounds__(256) void gemm_kernel(
    const float* __restrict__ A, const float* __restrict__ W,
    const float* __restrict__ bias, float* __restrict__ C,
    int M, int N, int K, int act)
{
    __shared__ float As[BK][68];   // padded: 68*4=272B rows keep float4 alignment, conflict-light
    __shared__ float Bs[BK][BN];
    int t = threadIdx.x;
    int m0 = blockIdx.y * BM, n0 = blockIdx.x * BN;
    int tm = (t >> 4) << 2;        // 0..60
    int tn = (t & 15) << 2;        // 0..60
    int ar = t >> 2;               // 0..63 (A tile row)
    int ac = (t & 3) << 2;         // 0,4,8,12 (A tile k-col)
    int br = t >> 4;               // 0..15 (B tile k-row)
    int bc = (t & 15) << 2;        // 0..60
    float acc[4][4] = {{0.f}};
    for (int k0 = 0; k0 < K; k0 += BK) {
        float4 av = *(const float4*)(A + (size_t)(m0 + ar) * K + k0 + ac);
        float4 bv = *(const float4*)(W + (size_t)(k0 + br) * N + n0 + bc);
        __syncthreads();
        As[ac + 0][ar] = av.x; As[ac + 1][ar] = av.y;
        As[ac + 2][ar] = av.z; As[ac + 3][ar] = av.w;
        *(float4*)&Bs[br][bc] = bv;
        __syncthreads();
#pragma unroll
        for (int kk = 0; kk < BK; ++kk) {
            float4 a  = *(float4*)&As[kk][tm];
            float4 bb = *(float4*)&Bs[kk][tn];
            acc[0][0] += a.x * bb.x; acc[0][1] += a.x * bb.y; acc[0][2] += a.x * bb.z; acc[0][3] += a.x * bb.w;
            acc[1][0] += a.y * bb.x; acc[1][1] += a.y * bb.y; acc[1][2] += a.y * bb.z; acc[1][3] += a.y * bb.w;
            acc[2][0] += a.z * bb.x; acc[2][1] += a.z * bb.y; acc[2][2] += a.z * bb.z; acc[2][3] += a.z * bb.w;
            acc[3][0] += a.w * bb.x; acc[3][1] += a.w * bb.y; acc[3][2] += a.w * bb.z; acc[3][3] += a.w * bb.w;
        }
    }
#pragma unroll
    for (int i = 0; i < 4; ++i) {
        float4 c;
        c.x = acc[i][0] + bias[n0 + tn + 0];
        c.y = acc[i][1] + bias[n0 + tn + 1];
        c.z = acc[i][2] + bias[n0 + tn + 2];
        c.w = acc[i][3] + bias[n0 + tn + 3];
        if (act == 1) {  // exact GELU
            c.x = 0.5f * c.x * (1.f + erff(c.x * 0.70710678118654752f));
            c.y = 0.5f * c.y * (1.f + erff(c.y * 0.70710678118654752f));
            c.z = 0.5f * c.z * (1.f + erff(c.z * 0.70710678118654752f));
            c.w = 0.5f * c.w * (1.f + erff(c.w * 0.70710678118654752f));
        }
        *(float4*)(C + (size_t)(m0 + tm + i) * N + n0 + tn) = c;
    }
}

// ---------------- attention: one wave per (query, b, h) ----------------
__global__ __launch_bounds__(64) void attn_kernel(
    const float* __restrict__ q, const float* __restrict__ k,
    const float* __restrict__ v, const int* __restrict__ mask,
    float* __restrict__ o, int B, int S)
{
    int sq = blockIdx.x, bh = blockIdx.y;
    int b = bh / Hc, h = bh % Hc;
    int t = threadIdx.x;  // 0..63
    __shared__ float qs[DHc];
    __shared__ float sc[256];      // S == 256
    __shared__ float Ks[64][65];   // +1 pad: conflict-free for both access patterns
    size_t base = (size_t)b * S * Dc + (size_t)h * DHc;
    qs[t] = q[base + (size_t)sq * Dc + t];
    __syncthreads();
    // scores
    for (int c0 = 0; c0 < S; c0 += 64) {
        for (int r = 0; r < 64; ++r)
            Ks[r][t] = k[base + (size_t)(c0 + r) * Dc + t];
        __syncthreads();
        float s = 0.f;
#pragma unroll
        for (int d = 0; d < DHc; ++d) s += qs[d] * Ks[t][d];
        int kk = c0 + t;
        sc[kk] = s * 0.125f + (1.0f - (float)mask[b * S + kk]) * -10000.0f;
        __syncthreads();
    }
    // softmax over sc[0..255] (each thread owns slots t, t+64, t+128, t+192)
    float m = fmaxf(fmaxf(sc[t], sc[t + 64]), fmaxf(sc[t + 128], sc[t + 192]));
#pragma unroll
    for (int off = 32; off > 0; off >>= 1) m = fmaxf(m, __shfl_xor(m, off, 64));
    float e0 = expf(sc[t] - m), e1 = expf(sc[t + 64] - m);
    float e2 = expf(sc[t + 128] - m), e3 = expf(sc[t + 192] - m);
    sc[t] = e0; sc[t + 64] = e1; sc[t + 128] = e2; sc[t + 192] = e3;
    float sum = e0 + e1 + e2 + e3;
#pragma unroll
    for (int off = 32; off > 0; off >>= 1) sum += __shfl_xor(sum, off, 64);
    float inv = 1.0f / sum;
    __syncthreads();
    // P @ V
    float acc = 0.f;
    for (int c0 = 0; c0 < S; c0 += 64) {
        for (int r = 0; r < 64; ++r)
            Ks[r][t] = v[base + (size_t)(c0 + r) * Dc + t];
        __syncthreads();
#pragma unroll
        for (int r = 0; r < 64; ++r) acc += sc[c0 + r] * Ks[r][t];
        __syncthreads();
    }
    o[base + (size_t)sq * Dc + t] = acc * inv;
}

// ---------------- final head ----------------
__global__ __launch_bounds__(64) void pun_proj_kernel(
    const float* __restrict__ x, const int* __restrict__ loc,
    const float* __restrict__ Wq, float* __restrict__ pq, int S)
{
    __shared__ float pun[Dc];
    int b = blockIdx.x, t = threadIdx.x;
    const float* row = x + ((size_t)b * S + loc[b]) * Dc;
    for (int i = t; i < Dc; i += 64) pun[i] = row[i];
    __syncthreads();
    float acc = 0.f;
    for (int d = 0; d < Dc; ++d) acc += pun[d] * Wq[(size_t)d * ATTc + t];
    pq[b * ATTc + t] = acc;
}

__global__ __launch_bounds__(64) void sense_proj_kernel(
    const float* __restrict__ se, const float* __restrict__ Wk,
    float* __restrict__ sk)
{
    __shared__ float srow[Dc];
    int i = blockIdx.x, t = threadIdx.x;
    const float* row = se + (size_t)i * Dc;
    for (int j = t; j < Dc; j += 64) srow[j] = row[j];
    __syncthreads();
    float acc = 0.f;
    for (int d = 0; d < Dc; ++d) acc += srow[d] * Wk[(size_t)d * ATTc + t];
    sk[i * ATTc + t] = acc;
}

// scores[b][i] = dot(pq[b], sk[i]); softmax + /8 are monotonic -> rank raw scores
__global__ __launch_bounds__(64) void top2_kernel(
    const float* __restrict__ pq, const float* __restrict__ sk,
    float* __restrict__ out)
{
    __shared__ float pqs[ATTc];
    __shared__ float scs[SENSEc];
    int b = blockIdx.x, t = threadIdx.x;
    pqs[t] = pq[b * ATTc + t];
    __syncthreads();
    float acc = 0.f;
#pragma unroll
    for (int d = 0; d < ATTc; ++d) acc += pqs[d] * sk[t * ATTc + d];
    scs[t] = acc;
    __syncthreads();
    if (t == 0) {
        float v1 = -INFINITY, v2 = -INFINITY;
        int i1 = 0, i2 = 0;
        for (int i = 0; i < SENSEc; ++i) {
            float s = scs[i];
            if (s > v1) { v2 = v1; i2 = i1; v1 = s; i1 = i; }
            else if (s > v2) { v2 = s; i2 = i; }
        }
        out[b * 2 + 0] = (float)i1;
        out[b * 2 + 1] = (float)i2;
    }
}

extern "C" void kernel_launch(void* const* d_in, const int* in_sizes, int n_in,
                              void* d_out, int out_size, void* d_ws, size_t ws_size,
                              hipStream_t stream)
{
    (void)n_in; (void)out_size; (void)ws_size;
    const int*   input_ids  = (const int*)d_in[0];
    const int*   token_type = (const int*)d_in[1];
    const int*   attn_mask  = (const int*)d_in[2];
    const int*   location   = (const int*)d_in[3];
    const float* sense_emb  = (const float*)d_in[4];
    const float* word_emb   = (const float*)d_in[5];
    const float* pos_emb    = (const float*)d_in[6];
    const float* type_emb   = (const float*)d_in[7];
    const float* eg         = (const float*)d_in[8];
    const float* eb         = (const float*)d_in[9];
    const float* Wq         = (const float*)d_in[10];
    const float* bq         = (const float*)d_in[11];
    const float* Wk         = (const float*)d_in[12];
    const float* bk         = (const float*)d_in[13];
    const float* Wv         = (const float*)d_in[14];
    const float* bv         = (const float*)d_in[15];
    const float* Wo         = (const float*)d_in[16];
    const float* bo         = (const float*)d_in[17];
    const float* ln1g       = (const float*)d_in[18];
    const float* ln1b       = (const float*)d_in[19];
    const float* W1         = (const float*)d_in[20];
    const float* b1         = (const float*)d_in[21];
    const float* W2         = (const float*)d_in[22];
    const float* b2         = (const float*)d_in[23];
    const float* ln2g       = (const float*)d_in[24];
    const float* ln2b       = (const float*)d_in[25];
    const float* attWq      = (const float*)d_in[26];
    const float* attWk      = (const float*)d_in[27];
    float* out = (float*)d_out;

    int B = in_sizes[3];      // 32
    int S = in_sizes[0] / B;  // 256
    int NT = B * S;           // 8192

    // workspace layout (floats): ~227 MB total
    float* ws = (float*)d_ws;
    float* x  = ws;                          // [NT, D]
    float* qb = x  + (size_t)NT * Dc;        // [NT, D]
    float* kb = qb + (size_t)NT * Dc;        // [NT, D]
    float* vb = kb + (size_t)NT * Dc;        // [NT, D]
    float* t1 = vb + (size_t)NT * Dc;        // [NT, D]  attn-out / W2-out
    float* t0 = t1 + (size_t)NT * Dc;        // [NT, FF] Wo-out / FFN hidden
    float* pq = t0 + (size_t)NT * FFc;       // [B, ATT]
    float* sk = pq + (size_t)B * ATTc;       // [SENSE, ATT]

    embed_kernel<<<NT, 256, 0, stream>>>(input_ids, token_type, word_emb,
                                         pos_emb, type_emb, eg, eb, x, S);

    dim3 gD(Dc / BN, NT / BM);   // 12 x 128
    dim3 gF(FFc / BN, NT / BM);  // 48 x 128
    for (int l = 0; l < Lc; ++l) {
        const float* wq = Wq + (size_t)l * Dc * Dc;
        const float* wk = Wk + (size_t)l * Dc * Dc;
        const float* wv = Wv + (size_t)l * Dc * Dc;
        const float* wo = Wo + (size_t)l * Dc * Dc;
        const float* w1 = W1 + (size_t)l * Dc * FFc;
        const float* w2 = W2 + (size_t)l * FFc * Dc;
        gemm_kernel<<<gD, 256, 0, stream>>>(x, wq, bq + l * Dc, qb, NT, Dc, Dc, 0);
        gemm_kernel<<<gD, 256, 0, stream>>>(x, wk, bk + l * Dc, kb, NT, Dc, Dc, 0);
        gemm_kernel<<<gD, 256, 0, stream>>>(x, wv, bv + l * Dc, vb, NT, Dc, Dc, 0);
        attn_kernel<<<dim3(S, B * Hc), 64, 0, stream>>>(qb, kb, vb, attn_mask, t1, B, S);
        gemm_kernel<<<gD, 256, 0, stream>>>(t1, wo, bo + l * Dc, t0, NT, Dc, Dc, 0);
        resln_kernel<<<NT, 256, 0, stream>>>(x, t0, ln1g + l * Dc, ln1b + l * Dc);
        gemm_kernel<<<gF, 256, 0, stream>>>(x, w1, b1 + l * FFc, t0, NT, FFc, Dc, 1);
        gemm_kernel<<<gD, 256, 0, stream>>>(t0, w2, b2 + l * Dc, t1, NT, Dc, FFc, 0);
        resln_kernel<<<NT, 256, 0, stream>>>(x, t1, ln2g + l * Dc, ln2b + l * Dc);
    }

    pun_proj_kernel<<<B, 64, 0, stream>>>(x, location, attWq, pq, S);
    sense_proj_kernel<<<SENSEc, 64, 0, stream>>>(sense_emb, attWk, sk);
    top2_kernel<<<B, 64, 0, stream>>>(pq, sk, out);
}

// Round 3
// 10007.472 us; speedup vs baseline: 4.6963x; 4.6963x over previous
//
#include <hip/hip_runtime.h>
#include <math.h>

typedef __attribute__((ext_vector_type(8))) short short8;
typedef __attribute__((ext_vector_type(4))) float f32x4;

static constexpr int Lc = 12;
static constexpr int Hc = 12;
static constexpr int Dc = 768;
static constexpr int DHc = 64;
static constexpr int FFc = 3072;
static constexpr int SENSEc = 64;
static constexpr int ATTc = 64;
static constexpr int QS = 3 * Dc;  // 2304 packed q|k|v

// fp32 -> bf16 RNE
__device__ __forceinline__ unsigned short f2bf(float f) {
    unsigned u = __float_as_uint(f);
    u = (u + 0x7FFFu + ((u >> 16) & 1u)) >> 16;
    return (unsigned short)u;
}
__device__ __forceinline__ float bf2f(unsigned short h) {
    return __uint_as_float((unsigned)h << 16);
}
// split v into hi + lo bf16 (lo = bf16(v - hi)); error ~2^-18 relative
__device__ __forceinline__ void splitbf(float v, unsigned short& h, unsigned short& l) {
    h = f2bf(v);
    l = f2bf(v - bf2f(h));
}

// async global->LDS, 16B/lane; lds dest = wave-uniform base + lane*16
__device__ __forceinline__ void load_lds16(const void* g, void* l) {
    __builtin_amdgcn_global_load_lds(
        (const __attribute__((address_space(1))) unsigned int*)g,
        (__attribute__((address_space(3))) unsigned int*)l, 16, 0, 0);
}

// ---------------- block reduction (256 threads = 4 waves) ----------------
__device__ __forceinline__ float blockReduceSum256(float v, float* sred) {
#pragma unroll
    for (int off = 32; off > 0; off >>= 1) v += __shfl_down(v, off, 64);
    int lane = threadIdx.x & 63, wid = threadIdx.x >> 6;
    if (lane == 0) sred[wid] = v;
    __syncthreads();
    float total = sred[0] + sred[1] + sred[2] + sred[3];
    __syncthreads();
    return total;
}

// ---------------- embedding + LayerNorm -> x fp32 + split bf16 planes ------------
__global__ __launch_bounds__(256) void embed_kernel(
    const int* __restrict__ ids, const int* __restrict__ tts,
    const float* __restrict__ we, const float* __restrict__ pe,
    const float* __restrict__ te, const float* __restrict__ g,
    const float* __restrict__ b, float* __restrict__ x,
    unsigned short* __restrict__ xh, unsigned short* __restrict__ xl, int S)
{
    int tok = blockIdx.x, t = threadIdx.x;
    int ss = tok % S;
    int id = ids[tok], tt = tts[tok];
    __shared__ float sred[4];
    float v[3];
    float s = 0.f;
#pragma unroll
    for (int i = 0; i < 3; ++i) {
        int d = t + i * 256;
        v[i] = we[(size_t)id * Dc + d] + pe[(size_t)ss * Dc + d] + te[(size_t)tt * Dc + d];
        s += v[i];
    }
    float mu = blockReduceSum256(s, sred) * (1.f / Dc);
    float s2 = 0.f;
#pragma unroll
    for (int i = 0; i < 3; ++i) { v[i] -= mu; s2 += v[i] * v[i]; }
    float rstd = rsqrtf(blockReduceSum256(s2, sred) * (1.f / Dc) + 1e-12f);
    size_t ro = (size_t)tok * Dc;
#pragma unroll
    for (int i = 0; i < 3; ++i) {
        int d = t + i * 256;
        float val = v[i] * rstd * g[d] + b[d];
        x[ro + d] = val;
        unsigned short hb_, lb_;
        splitbf(val, hb_, lb_);
        xh[ro + d] = hb_;
        xl[ro + d] = lb_;
    }
}

// ---------------- residual + LayerNorm (in-place x) + split planes ----------------
__global__ __launch_bounds__(256) void resln_kernel(
    float* __restrict__ x, const float* __restrict__ y,
    const float* __restrict__ g, const float* __restrict__ b,
    unsigned short* __restrict__ xh, unsigned short* __restrict__ xl)
{
    int tok = blockIdx.x, t = threadIdx.x;
    __shared__ float sred[4];
    size_t ro = (size_t)tok * Dc;
    float v[3];
    float s = 0.f;
#pragma unroll
    for (int i = 0; i < 3; ++i) {
        int d = t + i * 256;
        v[i] = x[ro + d] + y[ro + d];
        s += v[i];
    }
    float mu = blockReduceSum256(s, sred) * (1.f / Dc);
    float s2 = 0.f;
#pragma unroll
    for (int i = 0; i < 3; ++i) { v[i] -= mu; s2 += v[i] * v[i]; }
    float rstd = rsqrtf(blockReduceSum256(s2, sred) * (1.f / Dc) + 1e-12f);
#pragma unroll
    for (int i = 0; i < 3; ++i) {
        int d = t + i * 256;
        float val = v[i] * rstd * g[d] + b[d];
        x[ro + d] = val;
        unsigned short hb_, lb_;
        splitbf(val, hb_, lb_);
        xh[ro + d] = hb_;
        xl[ro + d] = lb_;
    }
}

// ------------- weight convert+transpose fp32 [K,N] -> split bf16 [N,K] planes -----
__global__ __launch_bounds__(256) void convert_weights(
    const float* __restrict__ Wq, const float* __restrict__ Wk,
    const float* __restrict__ Wv, const float* __restrict__ Wo,
    const float* __restrict__ W1, const float* __restrict__ W2,
    unsigned short* __restrict__ qh, unsigned short* __restrict__ ql,
    unsigned short* __restrict__ oh, unsigned short* __restrict__ ol,
    unsigned short* __restrict__ h1, unsigned short* __restrict__ l1,
    unsigned short* __restrict__ h2, unsigned short* __restrict__ l2)
{
    int id = blockIdx.x;
    const float* src; unsigned short *dh, *dl; int Kd, Nd, tx, ty;
    if (id < 576) {               // Wq,Wk,Wv (packed rows) + Wo : [768,768], 144 tiles each
        int m = id / 144, tile = id % 144;
        src = (m == 0) ? Wq : (m == 1) ? Wk : (m == 2) ? Wv : Wo;
        if (m < 3) { dh = qh + (size_t)m * Dc * Dc; dl = ql + (size_t)m * Dc * Dc; }
        else       { dh = oh; dl = ol; }
        Kd = Dc; Nd = Dc; tx = tile % 12; ty = tile / 12;
    } else if (id < 1152) {       // W1 [768,3072] -> [3072,768]
        int tile = id - 576;
        src = W1; dh = h1; dl = l1; Kd = Dc; Nd = FFc; tx = tile % 48; ty = tile / 48;
    } else {                      // W2 [3072,768] -> [768,3072]
        int tile = id - 1152;
        src = W2; dh = h2; dl = l2; Kd = FFc; Nd = Dc; tx = tile % 12; ty = tile / 12;
    }
    int k0 = ty * 64, n0 = tx * 64;
    __shared__ float tileS[64][65];
    int t = threadIdx.x, c = t & 63, r0 = t >> 6;
#pragma unroll
    for (int i = 0; i < 16; ++i) {
        int kr = r0 + i * 4;
        tileS[kr][c] = src[(size_t)(k0 + kr) * Nd + n0 + c];
    }
    __syncthreads();
#pragma unroll
    for (int i = 0; i < 16; ++i) {
        int nr = r0 + i * 4;
        float v = tileS[c][nr];
        unsigned short hb_, lb_;
        splitbf(v, hb_, lb_);
        size_t idx = (size_t)(n0 + nr) * Kd + k0 + c;
        dh[idx] = hb_;
        dl[idx] = lb_;
    }
}

// ---------------- packed qkv bias [L][2304] ----------------
__global__ __launch_bounds__(256) void biascat_kernel(
    const float* __restrict__ bq, const float* __restrict__ bk,
    const float* __restrict__ bv, float* __restrict__ out)
{
    int lyr = blockIdx.x, t = threadIdx.x;
    for (int j = t; j < QS; j += 256) {
        float v = (j < Dc) ? bq[lyr * Dc + j]
                : (j < 2 * Dc) ? bk[lyr * Dc + j - Dc]
                : bv[lyr * Dc + j - 2 * Dc];
        out[lyr * QS + j] = v;
    }
}

// ------------- split-bf16 MFMA GEMM: C = A @ Bt^T + bias -------------------------
// A = Ah+Al, B = Bh+Bl (bf16 planes, [M,K]/[N,K]); C ~= Ah.Bh + Ah.Bl + Al.Bh
// MODE 0: fp32 out.  MODE 1: GELU + split-bf16 out.
template <int MODE>
__global__ __launch_bounds__(256, 2) void mfma_gemm_split(
    const unsigned short* __restrict__ Ah, const unsigned short* __restrict__ Al,
    const unsigned short* __restrict__ Bh, const unsigned short* __restrict__ Bl,
    const float* __restrict__ bias, float* __restrict__ Cf,
    unsigned short* __restrict__ Ch, unsigned short* __restrict__ Cl,
    int M, int N, int K)
{
    __shared__ alignas(16) unsigned short Ash[128 * 64];
    __shared__ alignas(16) unsigned short Asl[128 * 64];
    __shared__ alignas(16) unsigned short Bsh[128 * 64];
    __shared__ alignas(16) unsigned short Bsl[128 * 64];
    int t = threadIdx.x, w = t >> 6, l = t & 63;
    int m0 = blockIdx.y * 128, n0 = blockIdx.x * 128;
    int wm = (w >> 1) * 64, wn = (w & 1) * 64;
    size_t go = (size_t)(w * 8 + (l >> 3)) * K + (size_t)(l & 7) * 8;
    const unsigned short* gah = Ah + (size_t)m0 * K + go;
    const unsigned short* gal = Al + (size_t)m0 * K + go;
    const unsigned short* gbh = Bh + (size_t)n0 * K + go;
    const unsigned short* gbl = Bl + (size_t)n0 * K + go;
    int lo = w * 512 + l * 8;
    f32x4 acc[4][4];
#pragma unroll
    for (int i = 0; i < 4; ++i)
#pragma unroll
        for (int j = 0; j < 4; ++j) acc[i][j] = (f32x4)0.f;
    int fm = l & 15, fq = (l >> 4) * 8;
    for (int k0 = 0; k0 < K; k0 += 64) {
        __syncthreads();
#pragma unroll
        for (int i = 0; i < 4; ++i) {
            size_t g = (size_t)(i * 32) * K + k0;
            int d = lo + i * 2048;
            load_lds16(gah + g, Ash + d);
            load_lds16(gal + g, Asl + d);
            load_lds16(gbh + g, Bsh + d);
            load_lds16(gbl + g, Bsl + d);
        }
        __syncthreads();
#pragma unroll
        for (int h = 0; h < 2; ++h) {
            short8 fah[4], fal[4], fbh[4], fbl[4];
#pragma unroll
            for (int i = 0; i < 4; ++i) {
                int ra = (wm + i * 16 + fm) * 64 + h * 32 + fq;
                int rb = (wn + i * 16 + fm) * 64 + h * 32 + fq;
                fah[i] = *(const short8*)(Ash + ra);
                fal[i] = *(const short8*)(Asl + ra);
                fbh[i] = *(const short8*)(Bsh + rb);
                fbl[i] = *(const short8*)(Bsl + rb);
            }
#pragma unroll
            for (int i = 0; i < 4; ++i)
#pragma unroll
                for (int j = 0; j < 4; ++j) {
                    acc[i][j] = __builtin_amdgcn_mfma_f32_16x16x32_bf16(
                        fah[i], fbh[j], acc[i][j], 0, 0, 0);
                    acc[i][j] = __builtin_amdgcn_mfma_f32_16x16x32_bf16(
                        fah[i], fbl[j], acc[i][j], 0, 0, 0);
                    acc[i][j] = __builtin_amdgcn_mfma_f32_16x16x32_bf16(
                        fal[i], fbh[j], acc[i][j], 0, 0, 0);
                }
        }
    }
    // C/D layout: col=lane&15, row=(lane>>4)*4+reg  [m89/m91 verified]
    int col_l = l & 15, row_l = (l >> 4) * 4;
#pragma unroll
    for (int j = 0; j < 4; ++j) {
        int col = n0 + wn + j * 16 + col_l;
        float bcv = bias[col];
#pragma unroll
        for (int i = 0; i < 4; ++i) {
            int row = m0 + wm + i * 16 + row_l;
#pragma unroll
            for (int r = 0; r < 4; ++r) {
                float v = acc[i][j][r] + bcv;
                size_t idx = (size_t)(row + r) * N + col;
                if (MODE == 1) {
                    v = 0.5f * v * (1.f + erff(v * 0.70710678118654752f));
                    unsigned short hb_, lb_;
                    splitbf(v, hb_, lb_);
                    Ch[idx] = hb_;
                    Cl[idx] = lb_;
                } else {
                    Cf[idx] = v;
                }
            }
        }
    }
}

// ------------- attention: 4 queries/block (1 per wave), shared K/V tiles ----------
__global__ __launch_bounds__(256) void attn_kernel4(
    const float* __restrict__ qkv, const int* __restrict__ mask,
    unsigned short* __restrict__ aoh, unsigned short* __restrict__ aol,
    int B, int S)
{
    int bh = blockIdx.y, b = bh / Hc, h = bh % Hc;
    int t = threadIdx.x, w = t >> 6, l = t & 63;
    int sq = blockIdx.x * 4 + w;
    __shared__ float Ks[64][65];
    __shared__ float qs[4][64];
    __shared__ float sc[4][256];
    size_t base = (size_t)b * S * QS + (size_t)h * DHc;
    qs[w][l] = qkv[base + (size_t)sq * QS + l];
    // scores: Q.K^T * scale + mask bias
    for (int c0 = 0; c0 < S; c0 += 64) {
        __syncthreads();
#pragma unroll
        for (int i = 0; i < 16; ++i)
            Ks[w * 16 + i][l] = qkv[base + Dc + (size_t)(c0 + w * 16 + i) * QS + l];
        __syncthreads();
        float s = 0.f;
#pragma unroll
        for (int d = 0; d < DHc; ++d) s += qs[w][d] * Ks[l][d];
        sc[w][c0 + l] = s * 0.125f + (1.0f - (float)mask[b * S + c0 + l]) * -10000.0f;
    }
    // softmax per wave (lane owns slots l, l+64, l+128, l+192)
    float m = fmaxf(fmaxf(sc[w][l], sc[w][l + 64]), fmaxf(sc[w][l + 128], sc[w][l + 192]));
#pragma unroll
    for (int off = 32; off > 0; off >>= 1) m = fmaxf(m, __shfl_xor(m, off, 64));
    float e0 = expf(sc[w][l] - m), e1 = expf(sc[w][l + 64] - m);
    float e2 = expf(sc[w][l + 128] - m), e3 = expf(sc[w][l + 192] - m);
    sc[w][l] = e0; sc[w][l + 64] = e1; sc[w][l + 128] = e2; sc[w][l + 192] = e3;
    float sum = e0 + e1 + e2 + e3;
#pragma unroll
    for (int off = 32; off > 0; off >>= 1) sum += __shfl_xor(sum, off, 64);
    float inv = 1.0f / sum;
    // P @ V  (lane l accumulates output dim l for query w)
    float acc = 0.f;
    for (int c0 = 0; c0 < S; c0 += 64) {
        __syncthreads();
#pragma unroll
        for (int i = 0; i < 16; ++i)
            Ks[w * 16 + i][l] = qkv[base + 2 * Dc + (size_t)(c0 + w * 16 + i) * QS + l];
        __syncthreads();
#pragma unroll
        for (int r = 0; r < 64; ++r) acc += sc[w][c0 + r] * Ks[r][l];
    }
    float o = acc * inv;
    size_t oi = ((size_t)(b * S + sq)) * Dc + (size_t)h * DHc + l;
    unsigned short hb_, lb_;
    splitbf(o, hb_, lb_);
    aoh[oi] = hb_;
    aol[oi] = lb_;
}

// ---------------- final head (fp32 from fp32 master) ----------------
__global__ __launch_bounds__(64) void pun_proj_kernel(
    const float* __restrict__ x, const int* __restrict__ loc,
    const float* __restrict__ Wq, float* __restrict__ pq, int S)
{
    __shared__ float pun[Dc];
    int b = blockIdx.x, t = threadIdx.x;
    const float* row = x + ((size_t)b * S + loc[b]) * Dc;
    for (int i = t; i < Dc; i += 64) pun[i] = row[i];
    __syncthreads();
    float acc = 0.f;
    for (int d = 0; d < Dc; ++d) acc += pun[d] * Wq[(size_t)d * ATTc + t];
    pq[b * ATTc + t] = acc;
}

__global__ __launch_bounds__(64) void sense_proj_kernel(
    const float* __restrict__ se, const float* __restrict__ Wk,
    float* __restrict__ sk)
{
    __shared__ float srow[Dc];
    int i = blockIdx.x, t = threadIdx.x;
    const float* row = se + (size_t)i * Dc;
    for (int j = t; j < Dc; j += 64) srow[j] = row[j];
    __syncthreads();
    float acc = 0.f;
    for (int d = 0; d < Dc; ++d) acc += srow[d] * Wk[(size_t)d * ATTc + t];
    sk[i * ATTc + t] = acc;
}

__global__ __launch_bounds__(64) void top2_kernel(
    const float* __restrict__ pq, const float* __restrict__ sk,
    float* __restrict__ out)
{
    __shared__ float pqs[ATTc];
    __shared__ float scs[SENSEc];
    int b = blockIdx.x, t = threadIdx.x;
    pqs[t] = pq[b * ATTc + t];
    __syncthreads();
    float acc = 0.f;
#pragma unroll
    for (int d = 0; d < ATTc; ++d) acc += pqs[d] * sk[t * ATTc + d];
    scs[t] = acc;
    __syncthreads();
    if (t == 0) {
        float v1 = -INFINITY, v2 = -INFINITY;
        int i1 = 0, i2 = 0;
        for (int i = 0; i < SENSEc; ++i) {
            float s = scs[i];
            if (s > v1) { v2 = v1; i2 = i1; v1 = s; i1 = i; }
            else if (s > v2) { v2 = s; i2 = i; }
        }
        out[b * 2 + 0] = (float)i1;
        out[b * 2 + 1] = (float)i2;
    }
}

extern "C" void kernel_launch(void* const* d_in, const int* in_sizes, int n_in,
                              void* d_out, int out_size, void* d_ws, size_t ws_size,
                              hipStream_t stream)
{
    (void)n_in; (void)out_size; (void)ws_size;
    const int*   input_ids  = (const int*)d_in[0];
    const int*   token_type = (const int*)d_in[1];
    const int*   attn_mask  = (const int*)d_in[2];
    const int*   location   = (const int*)d_in[3];
    const float* sense_emb  = (const float*)d_in[4];
    const float* word_emb   = (const float*)d_in[5];
    const float* pos_emb    = (const float*)d_in[6];
    const float* type_emb   = (const float*)d_in[7];
    const float* eg         = (const float*)d_in[8];
    const float* eb         = (const float*)d_in[9];
    const float* Wq         = (const float*)d_in[10];
    const float* bq         = (const float*)d_in[11];
    const float* Wk         = (const float*)d_in[12];
    const float* bk         = (const float*)d_in[13];
    const float* Wv         = (const float*)d_in[14];
    const float* bv         = (const float*)d_in[15];
    const float* Wo         = (const float*)d_in[16];
    const float* bo         = (const float*)d_in[17];
    const float* ln1g       = (const float*)d_in[18];
    const float* ln1b       = (const float*)d_in[19];
    const float* W1         = (const float*)d_in[20];
    const float* b1         = (const float*)d_in[21];
    const float* W2         = (const float*)d_in[22];
    const float* b2         = (const float*)d_in[23];
    const float* ln2g       = (const float*)d_in[24];
    const float* ln2b       = (const float*)d_in[25];
    const float* attWq      = (const float*)d_in[26];
    const float* attWk      = (const float*)d_in[27];
    float* out = (float*)d_out;

    int B = in_sizes[3];      // 32
    int S = in_sizes[0] / B;  // 256
    int NT = B * S;           // 8192
    size_t NTD = (size_t)NT * Dc;

    // ---- workspace layout (~205 MB) with liveness aliasing ----
    float*          x   = (float*)d_ws;                         // [NT,D] fp32 master
    unsigned short* xh  = (unsigned short*)(x + NTD);           // [NT,D]
    unsigned short* xl  = xh + NTD;                             // [NT,D]
    float*          y   = (float*)(xl + NTD);                   // [NT,D] fp32
    // scratch union: {qkv fp32 + aoh/aol}  <->  {hh/hl}
    float*          qkv = (float*)(y + NTD);                    // [NT,2304] fp32
    unsigned short* aoh = (unsigned short*)(qkv + (size_t)NT * QS);
    unsigned short* aol = aoh + NTD;
    unsigned short* hh  = (unsigned short*)qkv;                 // [NT,FF] (aliases qkv/ao)
    unsigned short* hl  = hh + (size_t)NT * FFc;
    // persistent small
    float*          bc  = (float*)(aol + NTD);                  // [L,2304]
    unsigned short* wqh = (unsigned short*)(bc + (size_t)Lc * QS);
    unsigned short* wql = wqh + (size_t)QS * Dc;
    unsigned short* woh = wql + (size_t)QS * Dc;
    unsigned short* wol = woh + (size_t)Dc * Dc;
    unsigned short* w1h = wol + (size_t)Dc * Dc;
    unsigned short* w1l = w1h + (size_t)FFc * Dc;
    unsigned short* w2h = w1l + (size_t)FFc * Dc;
    unsigned short* w2l = w2h + (size_t)Dc * FFc;
    float*          pq  = (float*)(w2l + (size_t)Dc * FFc);
    float*          sk  = pq + (size_t)B * ATTc;

    embed_kernel<<<NT, 256, 0, stream>>>(input_ids, token_type, word_emb,
                                         pos_emb, type_emb, eg, eb, x, xh, xl, S);
    biascat_kernel<<<Lc, 256, 0, stream>>>(bq, bk, bv, bc);

    dim3 gQKV(QS / 128, NT / 128);   // 18 x 64
    dim3 gD(Dc / 128, NT / 128);     // 6 x 64
    dim3 gF(FFc / 128, NT / 128);    // 24 x 64
    for (int l = 0; l < Lc; ++l) {
        convert_weights<<<1728, 256, 0, stream>>>(
            Wq + (size_t)l * Dc * Dc, Wk + (size_t)l * Dc * Dc,
            Wv + (size_t)l * Dc * Dc, Wo + (size_t)l * Dc * Dc,
            W1 + (size_t)l * Dc * FFc, W2 + (size_t)l * FFc * Dc,
            wqh, wql, woh, wol, w1h, w1l, w2h, w2l);
        mfma_gemm_split<0><<<gQKV, 256, 0, stream>>>(
            xh, xl, wqh, wql, bc + (size_t)l * QS, qkv, nullptr, nullptr, NT, QS, Dc);
        attn_kernel4<<<dim3(S / 4, B * Hc), 256, 0, stream>>>(qkv, attn_mask,
                                                              aoh, aol, B, S);
        mfma_gemm_split<0><<<gD, 256, 0, stream>>>(
            aoh, aol, woh, wol, bo + (size_t)l * Dc, y, nullptr, nullptr, NT, Dc, Dc);
        resln_kernel<<<NT, 256, 0, stream>>>(x, y, ln1g + (size_t)l * Dc,
                                             ln1b + (size_t)l * Dc, xh, xl);
        mfma_gemm_split<1><<<gF, 256, 0, stream>>>(
            xh, xl, w1h, w1l, b1 + (size_t)l * FFc, nullptr, hh, hl, NT, FFc, Dc);
        mfma_gemm_split<0><<<gD, 256, 0, stream>>>(
            hh, hl, w2h, w2l, b2 + (size_t)l * Dc, y, nullptr, nullptr, NT, Dc, FFc);
        resln_kernel<<<NT, 256, 0, stream>>>(x, y, ln2g + (size_t)l * Dc,
                                             ln2b + (size_t)l * Dc, xh, xl);
    }

    pun_proj_kernel<<<B, 64, 0, stream>>>(x, location, attWq, pq, S);
    sense_proj_kernel<<<SENSEc, 64, 0, stream>>>(sense_emb, attWk, sk);
    top2_kernel<<<B, 64, 0, stream>>>(pq, sk, out);
}

// Round 4
// 6784.744 us; speedup vs baseline: 6.9271x; 1.4750x over previous
//
#include <hip/hip_runtime.h>
#include <math.h>

typedef __attribute__((ext_vector_type(8))) short short8;
typedef __attribute__((ext_vector_type(4))) float f32x4;

static constexpr int Lc = 12;
static constexpr int Hc = 12;
static constexpr int Dc = 768;
static constexpr int DHc = 64;
static constexpr int FFc = 3072;
static constexpr int SENSEc = 64;
static constexpr int ATTc = 64;
static constexpr int QS = 3 * Dc;   // 2304 packed q|k|v
static constexpr int KPAD = 72;     // LDS row stride (shorts): 144B, 16B-aligned, bank-rotating

// fp32 -> bf16 RNE
__device__ __forceinline__ unsigned short f2bf(float f) {
    unsigned u = __float_as_uint(f);
    u = (u + 0x7FFFu + ((u >> 16) & 1u)) >> 16;
    return (unsigned short)u;
}
__device__ __forceinline__ float bf2f(unsigned short h) {
    return __uint_as_float((unsigned)h << 16);
}
__device__ __forceinline__ void splitbf(float v, unsigned short& h, unsigned short& l) {
    h = f2bf(v);
    l = f2bf(v - bf2f(h));
}

__device__ __forceinline__ void load_lds16(const void* g, void* l) {
    __builtin_amdgcn_global_load_lds(
        (const __attribute__((address_space(1))) unsigned int*)g,
        (__attribute__((address_space(3))) unsigned int*)l, 16, 0, 0);
}

// ---------------- block reduction (256 threads = 4 waves) ----------------
__device__ __forceinline__ float blockReduceSum256(float v, float* sred) {
#pragma unroll
    for (int off = 32; off > 0; off >>= 1) v += __shfl_down(v, off, 64);
    int lane = threadIdx.x & 63, wid = threadIdx.x >> 6;
    if (lane == 0) sred[wid] = v;
    __syncthreads();
    float total = sred[0] + sred[1] + sred[2] + sred[3];
    __syncthreads();
    return total;
}

// ---------------- embedding + LayerNorm -> x fp32 + split bf16 planes ------------
__global__ __launch_bounds__(256) void embed_kernel(
    const int* __restrict__ ids, const int* __restrict__ tts,
    const float* __restrict__ we, const float* __restrict__ pe,
    const float* __restrict__ te, const float* __restrict__ g,
    const float* __restrict__ b, float* __restrict__ x,
    unsigned short* __restrict__ xh, unsigned short* __restrict__ xl, int S)
{
    int tok = blockIdx.x, t = threadIdx.x;
    int ss = tok % S;
    int id = ids[tok], tt = tts[tok];
    __shared__ float sred[4];
    float v[3];
    float s = 0.f;
#pragma unroll
    for (int i = 0; i < 3; ++i) {
        int d = t + i * 256;
        v[i] = we[(size_t)id * Dc + d] + pe[(size_t)ss * Dc + d] + te[(size_t)tt * Dc + d];
        s += v[i];
    }
    float mu = blockReduceSum256(s, sred) * (1.f / Dc);
    float s2 = 0.f;
#pragma unroll
    for (int i = 0; i < 3; ++i) { v[i] -= mu; s2 += v[i] * v[i]; }
    float rstd = rsqrtf(blockReduceSum256(s2, sred) * (1.f / Dc) + 1e-12f);
    size_t ro = (size_t)tok * Dc;
#pragma unroll
    for (int i = 0; i < 3; ++i) {
        int d = t + i * 256;
        float val = v[i] * rstd * g[d] + b[d];
        x[ro + d] = val;
        unsigned short hb_, lb_;
        splitbf(val, hb_, lb_);
        xh[ro + d] = hb_;
        xl[ro + d] = lb_;
    }
}

// ---------------- residual + LayerNorm (in-place x) + split planes ----------------
__global__ __launch_bounds__(256) void resln_kernel(
    float* __restrict__ x, const float* __restrict__ y,
    const float* __restrict__ g, const float* __restrict__ b,
    unsigned short* __restrict__ xh, unsigned short* __restrict__ xl)
{
    int tok = blockIdx.x, t = threadIdx.x;
    __shared__ float sred[4];
    size_t ro = (size_t)tok * Dc;
    float v[3];
    float s = 0.f;
#pragma unroll
    for (int i = 0; i < 3; ++i) {
        int d = t + i * 256;
        v[i] = x[ro + d] + y[ro + d];
        s += v[i];
    }
    float mu = blockReduceSum256(s, sred) * (1.f / Dc);
    float s2 = 0.f;
#pragma unroll
    for (int i = 0; i < 3; ++i) { v[i] -= mu; s2 += v[i] * v[i]; }
    float rstd = rsqrtf(blockReduceSum256(s2, sred) * (1.f / Dc) + 1e-12f);
#pragma unroll
    for (int i = 0; i < 3; ++i) {
        int d = t + i * 256;
        float val = v[i] * rstd * g[d] + b[d];
        x[ro + d] = val;
        unsigned short hb_, lb_;
        splitbf(val, hb_, lb_);
        xh[ro + d] = hb_;
        xl[ro + d] = lb_;
    }
}

// ------------- weight convert+transpose fp32 [K,N] -> split bf16 [N,K] planes -----
__global__ __launch_bounds__(256) void convert_weights(
    const float* __restrict__ Wq, const float* __restrict__ Wk,
    const float* __restrict__ Wv, const float* __restrict__ Wo,
    const float* __restrict__ W1, const float* __restrict__ W2,
    unsigned short* __restrict__ qh, unsigned short* __restrict__ ql,
    unsigned short* __restrict__ oh, unsigned short* __restrict__ ol,
    unsigned short* __restrict__ h1, unsigned short* __restrict__ l1,
    unsigned short* __restrict__ h2, unsigned short* __restrict__ l2)
{
    int id = blockIdx.x;
    const float* src; unsigned short *dh, *dl; int Kd, Nd, tx, ty;
    if (id < 576) {
        int m = id / 144, tile = id % 144;
        src = (m == 0) ? Wq : (m == 1) ? Wk : (m == 2) ? Wv : Wo;
        if (m < 3) { dh = qh + (size_t)m * Dc * Dc; dl = ql + (size_t)m * Dc * Dc; }
        else       { dh = oh; dl = ol; }
        Kd = Dc; Nd = Dc; tx = tile % 12; ty = tile / 12;
    } else if (id < 1152) {
        int tile = id - 576;
        src = W1; dh = h1; dl = l1; Kd = Dc; Nd = FFc; tx = tile % 48; ty = tile / 48;
    } else {
        int tile = id - 1152;
        src = W2; dh = h2; dl = l2; Kd = FFc; Nd = Dc; tx = tile % 12; ty = tile / 12;
    }
    int k0 = ty * 64, n0 = tx * 64;
    __shared__ float tileS[64][65];
    int t = threadIdx.x, c = t & 63, r0 = t >> 6;
#pragma unroll
    for (int i = 0; i < 16; ++i) {
        int kr = r0 + i * 4;
        tileS[kr][c] = src[(size_t)(k0 + kr) * Nd + n0 + c];
    }
    __syncthreads();
#pragma unroll
    for (int i = 0; i < 16; ++i) {
        int nr = r0 + i * 4;
        float v = tileS[c][nr];
        unsigned short hb_, lb_;
        splitbf(v, hb_, lb_);
        size_t idx = (size_t)(n0 + nr) * Kd + k0 + c;
        dh[idx] = hb_;
        dl[idx] = lb_;
    }
}

// ---------------- packed qkv bias [L][2304] ----------------
__global__ __launch_bounds__(256) void biascat_kernel(
    const float* __restrict__ bq, const float* __restrict__ bk,
    const float* __restrict__ bv, float* __restrict__ out)
{
    int lyr = blockIdx.x, t = threadIdx.x;
    for (int j = t; j < QS; j += 256) {
        float v = (j < Dc) ? bq[lyr * Dc + j]
                : (j < 2 * Dc) ? bk[lyr * Dc + j - Dc]
                : bv[lyr * Dc + j - 2 * Dc];
        out[lyr * QS + j] = v;
    }
}

// ------------- split-bf16 MFMA GEMM: C = A @ Bt^T + bias -------------------------
template <int MODE>
__global__ __launch_bounds__(256, 2) void mfma_gemm_split(
    const unsigned short* __restrict__ Ah, const unsigned short* __restrict__ Al,
    const unsigned short* __restrict__ Bh, const unsigned short* __restrict__ Bl,
    const float* __restrict__ bias, float* __restrict__ Cf,
    unsigned short* __restrict__ Ch, unsigned short* __restrict__ Cl,
    int M, int N, int K)
{
    __shared__ alignas(16) unsigned short Ash[128 * 64];
    __shared__ alignas(16) unsigned short Asl[128 * 64];
    __shared__ alignas(16) unsigned short Bsh[128 * 64];
    __shared__ alignas(16) unsigned short Bsl[128 * 64];
    int t = threadIdx.x, w = t >> 6, l = t & 63;
    int m0 = blockIdx.y * 128, n0 = blockIdx.x * 128;
    int wm = (w >> 1) * 64, wn = (w & 1) * 64;
    size_t go = (size_t)(w * 8 + (l >> 3)) * K + (size_t)(l & 7) * 8;
    const unsigned short* gah = Ah + (size_t)m0 * K + go;
    const unsigned short* gal = Al + (size_t)m0 * K + go;
    const unsigned short* gbh = Bh + (size_t)n0 * K + go;
    const unsigned short* gbl = Bl + (size_t)n0 * K + go;
    int lo = w * 512 + l * 8;
    f32x4 acc[4][4];
#pragma unroll
    for (int i = 0; i < 4; ++i)
#pragma unroll
        for (int j = 0; j < 4; ++j) acc[i][j] = (f32x4)0.f;
    int fm = l & 15, fq = (l >> 4) * 8;
    for (int k0 = 0; k0 < K; k0 += 64) {
        __syncthreads();
#pragma unroll
        for (int i = 0; i < 4; ++i) {
            size_t g = (size_t)(i * 32) * K + k0;
            int d = lo + i * 2048;
            load_lds16(gah + g, Ash + d);
            load_lds16(gal + g, Asl + d);
            load_lds16(gbh + g, Bsh + d);
            load_lds16(gbl + g, Bsl + d);
        }
        __syncthreads();
#pragma unroll
        for (int h = 0; h < 2; ++h) {
            short8 fah[4], fal[4], fbh[4], fbl[4];
#pragma unroll
            for (int i = 0; i < 4; ++i) {
                int ra = (wm + i * 16 + fm) * 64 + h * 32 + fq;
                int rb = (wn + i * 16 + fm) * 64 + h * 32 + fq;
                fah[i] = *(const short8*)(Ash + ra);
                fal[i] = *(const short8*)(Asl + ra);
                fbh[i] = *(const short8*)(Bsh + rb);
                fbl[i] = *(const short8*)(Bsl + rb);
            }
#pragma unroll
            for (int i = 0; i < 4; ++i)
#pragma unroll
                for (int j = 0; j < 4; ++j) {
                    acc[i][j] = __builtin_amdgcn_mfma_f32_16x16x32_bf16(
                        fah[i], fbh[j], acc[i][j], 0, 0, 0);
                    acc[i][j] = __builtin_amdgcn_mfma_f32_16x16x32_bf16(
                        fah[i], fbl[j], acc[i][j], 0, 0, 0);
                    acc[i][j] = __builtin_amdgcn_mfma_f32_16x16x32_bf16(
                        fal[i], fbh[j], acc[i][j], 0, 0, 0);
                }
        }
    }
    int col_l = l & 15, row_l = (l >> 4) * 4;
#pragma unroll
    for (int j = 0; j < 4; ++j) {
        int col = n0 + wn + j * 16 + col_l;
        float bcv = bias[col];
#pragma unroll
        for (int i = 0; i < 4; ++i) {
            int row = m0 + wm + i * 16 + row_l;
#pragma unroll
            for (int r = 0; r < 4; ++r) {
                float v = acc[i][j][r] + bcv;
                size_t idx = (size_t)(row + r) * N + col;
                if (MODE == 1) {
                    v = 0.5f * v * (1.f + erff(v * 0.70710678118654752f));
                    unsigned short hb_, lb_;
                    splitbf(v, hb_, lb_);
                    Ch[idx] = hb_;
                    Cl[idx] = lb_;
                } else {
                    Cf[idx] = v;
                }
            }
        }
    }
}

// ------------- MFMA flash attention: one block per (b,head), 4 waves ------------
// Wave w handles queries [64w, 64w+64). K/V^T staged bf16 in LDS (stride KPAD).
// Per 64-key chunk: scores = Q.K^T (MFMA) -> fp32 online softmax (width-16
// shuffles over C-layout rows) -> P to LDS (A-layout round-trip) -> O += P.V
// (MFMA). fp32 O accumulator; epilogue writes split-bf16 planes for Wo GEMM.
__global__ __launch_bounds__(256, 1) void attn_mfma(
    const float* __restrict__ qkv, const int* __restrict__ mask,
    unsigned short* __restrict__ aoh, unsigned short* __restrict__ aol,
    int B, int S)
{
    int bh = blockIdx.x, b = bh / Hc, hd = bh % Hc;
    int t = threadIdx.x, w = t >> 6, l = t & 63;
    int grp = l >> 4, lc = l & 15;
    __shared__ alignas(16) unsigned short Ks[256 * KPAD];     // [key][d]
    __shared__ alignas(16) unsigned short Vts[4][64 * KPAD];  // [chunk][d][key%64]
    __shared__ alignas(16) unsigned short Pw[4][64 * KPAD];   // [wave][q%64][key%64]
    __shared__ float mb[256];
    size_t rowbase = (size_t)(b * S) * QS;

    mb[t] = (1.f - (float)mask[b * S + t]) * -10000.0f;

    // ---- stage K rows and V^T panels (fp32 -> bf16) ----
    for (int p = 0; p < 4; ++p) {
        int key = p * 64 + (t >> 2);
        int d0 = (t & 3) * 16;
        const float* ksrc = qkv + rowbase + (size_t)key * QS + Dc + hd * DHc + d0;
        float kt[16];
        *(float4*)(kt + 0)  = *(const float4*)(ksrc + 0);
        *(float4*)(kt + 4)  = *(const float4*)(ksrc + 4);
        *(float4*)(kt + 8)  = *(const float4*)(ksrc + 8);
        *(float4*)(kt + 12) = *(const float4*)(ksrc + 12);
        short8 s0, s1;
#pragma unroll
        for (int u = 0; u < 8; ++u) { s0[u] = (short)f2bf(kt[u]); s1[u] = (short)f2bf(kt[u + 8]); }
        *(short8*)(Ks + key * KPAD + d0) = s0;
        *(short8*)(Ks + key * KPAD + d0 + 8) = s1;
        const float* vsrc = qkv + rowbase + (size_t)key * QS + 2 * Dc + hd * DHc + d0;
        float vt[16];
        *(float4*)(vt + 0)  = *(const float4*)(vsrc + 0);
        *(float4*)(vt + 4)  = *(const float4*)(vsrc + 4);
        *(float4*)(vt + 8)  = *(const float4*)(vsrc + 8);
        *(float4*)(vt + 12) = *(const float4*)(vsrc + 12);
        int kk = t >> 2;
#pragma unroll
        for (int u = 0; u < 16; ++u)
            Vts[p][(d0 + u) * KPAD + kk] = f2bf(vt[u]);
    }

    // ---- load Q fragments into registers (A-layout: m=lc, k=grp*8+j) ----
    int q0 = w * 64;
    short8 qf[4][2];
#pragma unroll
    for (int i = 0; i < 4; ++i)
#pragma unroll
        for (int kc = 0; kc < 2; ++kc) {
            const float* qsrc = qkv + rowbase + (size_t)(q0 + 16 * i + lc) * QS
                              + hd * DHc + kc * 32 + grp * 8;
            float4 a = *(const float4*)qsrc;
            float4 c4 = *(const float4*)(qsrc + 4);
            short8 f;
            f[0] = (short)f2bf(a.x);  f[1] = (short)f2bf(a.y);
            f[2] = (short)f2bf(a.z);  f[3] = (short)f2bf(a.w);
            f[4] = (short)f2bf(c4.x); f[5] = (short)f2bf(c4.y);
            f[6] = (short)f2bf(c4.z); f[7] = (short)f2bf(c4.w);
            qf[i][kc] = f;
        }
    __syncthreads();

    f32x4 oacc[4][4];
#pragma unroll
    for (int i = 0; i < 4; ++i)
#pragma unroll
        for (int j = 0; j < 4; ++j) oacc[i][j] = (f32x4)0.f;
    float mstate[4][4], lstate[4][4];
#pragma unroll
    for (int i = 0; i < 4; ++i)
#pragma unroll
        for (int r = 0; r < 4; ++r) { mstate[i][r] = -3.0e38f; lstate[i][r] = 0.f; }

    for (int c = 0; c < 4; ++c) {
        // scores chunk: S[64q x 64k]
        f32x4 sacc[4][4];
#pragma unroll
        for (int i = 0; i < 4; ++i)
#pragma unroll
            for (int j = 0; j < 4; ++j) sacc[i][j] = (f32x4)0.f;
#pragma unroll
        for (int kc = 0; kc < 2; ++kc) {
            short8 kf[4];
#pragma unroll
            for (int j = 0; j < 4; ++j)
                kf[j] = *(const short8*)(Ks + (c * 64 + 16 * j + lc) * KPAD + kc * 32 + grp * 8);
#pragma unroll
            for (int i = 0; i < 4; ++i)
#pragma unroll
                for (int j = 0; j < 4; ++j)
                    sacc[i][j] = __builtin_amdgcn_mfma_f32_16x16x32_bf16(
                        qf[i][kc], kf[j], sacc[i][j], 0, 0, 0);
        }
        // scale + mask bias
#pragma unroll
        for (int j = 0; j < 4; ++j) {
            float mbv = mb[c * 64 + 16 * j + lc];
#pragma unroll
            for (int i = 0; i < 4; ++i)
#pragma unroll
                for (int r = 0; r < 4; ++r)
                    sacc[i][j][r] = sacc[i][j][r] * 0.125f + mbv;
        }
        // online softmax per row (row = 16i + 4*grp + r, spread over 16 lanes)
#pragma unroll
        for (int i = 0; i < 4; ++i)
#pragma unroll
            for (int r = 0; r < 4; ++r) {
                float cm = fmaxf(fmaxf(sacc[i][0][r], sacc[i][1][r]),
                                 fmaxf(sacc[i][2][r], sacc[i][3][r]));
#pragma unroll
                for (int mw = 1; mw < 16; mw <<= 1)
                    cm = fmaxf(cm, __shfl_xor(cm, mw, 16));
                float nm = fmaxf(mstate[i][r], cm);
                float alpha = expf(mstate[i][r] - nm);
                mstate[i][r] = nm;
                float rs = 0.f;
#pragma unroll
                for (int j = 0; j < 4; ++j) {
                    float p = expf(sacc[i][j][r] - nm);
                    sacc[i][j][r] = p;
                    rs += p;
                }
#pragma unroll
                for (int mw = 1; mw < 16; mw <<= 1)
                    rs += __shfl_xor(rs, mw, 16);
                lstate[i][r] = lstate[i][r] * alpha + rs;
#pragma unroll
                for (int j = 0; j < 4; ++j) oacc[i][j][r] *= alpha;
            }
        // write P (C-layout -> LDS row-major [q][k])
#pragma unroll
        for (int i = 0; i < 4; ++i)
#pragma unroll
            for (int j = 0; j < 4; ++j)
#pragma unroll
                for (int r = 0; r < 4; ++r)
                    Pw[w][(16 * i + 4 * grp + r) * KPAD + 16 * j + lc] =
                        f2bf(sacc[i][j][r]);
        __syncthreads();
        // O += P @ V  (A-frags from Pw, B-frags from Vts panel c)
#pragma unroll
        for (int kc = 0; kc < 2; ++kc) {
            short8 pf[4], vf[4];
#pragma unroll
            for (int i = 0; i < 4; ++i)
                pf[i] = *(const short8*)(&Pw[w][(16 * i + lc) * KPAD + kc * 32 + grp * 8]);
#pragma unroll
            for (int j = 0; j < 4; ++j)
                vf[j] = *(const short8*)(&Vts[c][(16 * j + lc) * KPAD + kc * 32 + grp * 8]);
#pragma unroll
            for (int i = 0; i < 4; ++i)
#pragma unroll
                for (int j = 0; j < 4; ++j)
                    oacc[i][j] = __builtin_amdgcn_mfma_f32_16x16x32_bf16(
                        pf[i], vf[j], oacc[i][j], 0, 0, 0);
        }
        __syncthreads();
    }
    // epilogue: normalize, split-bf16 out
#pragma unroll
    for (int i = 0; i < 4; ++i)
#pragma unroll
        for (int r = 0; r < 4; ++r) {
            float inv = 1.f / lstate[i][r];
            size_t tok = (size_t)(b * S + q0 + 16 * i + 4 * grp + r);
#pragma unroll
            for (int j = 0; j < 4; ++j) {
                float v = oacc[i][j][r] * inv;
                size_t idx = tok * Dc + hd * DHc + 16 * j + lc;
                unsigned short hb_, lb_;
                splitbf(v, hb_, lb_);
                aoh[idx] = hb_;
                aol[idx] = lb_;
            }
        }
}

// ---------------- final head (fp32 from fp32 master) ----------------
__global__ __launch_bounds__(64) void pun_proj_kernel(
    const float* __restrict__ x, const int* __restrict__ loc,
    const float* __restrict__ Wq, float* __restrict__ pq, int S)
{
    __shared__ float pun[Dc];
    int b = blockIdx.x, t = threadIdx.x;
    const float* row = x + ((size_t)b * S + loc[b]) * Dc;
    for (int i = t; i < Dc; i += 64) pun[i] = row[i];
    __syncthreads();
    float acc = 0.f;
    for (int d = 0; d < Dc; ++d) acc += pun[d] * Wq[(size_t)d * ATTc + t];
    pq[b * ATTc + t] = acc;
}

__global__ __launch_bounds__(64) void sense_proj_kernel(
    const float* __restrict__ se, const float* __restrict__ Wk,
    float* __restrict__ sk)
{
    __shared__ float srow[Dc];
    int i = blockIdx.x, t = threadIdx.x;
    const float* row = se + (size_t)i * Dc;
    for (int j = t; j < Dc; j += 64) srow[j] = row[j];
    __syncthreads();
    float acc = 0.f;
    for (int d = 0; d < Dc; ++d) acc += srow[d] * Wk[(size_t)d * ATTc + t];
    sk[i * ATTc + t] = acc;
}

__global__ __launch_bounds__(64) void top2_kernel(
    const float* __restrict__ pq, const float* __restrict__ sk,
    float* __restrict__ out)
{
    __shared__ float pqs[ATTc];
    __shared__ float scs[SENSEc];
    int b = blockIdx.x, t = threadIdx.x;
    pqs[t] = pq[b * ATTc + t];
    __syncthreads();
    float acc = 0.f;
#pragma unroll
    for (int d = 0; d < ATTc; ++d) acc += pqs[d] * sk[t * ATTc + d];
    scs[t] = acc;
    __syncthreads();
    if (t == 0) {
        float v1 = -INFINITY, v2 = -INFINITY;
        int i1 = 0, i2 = 0;
        for (int i = 0; i < SENSEc; ++i) {
            float s = scs[i];
            if (s > v1) { v2 = v1; i2 = i1; v1 = s; i1 = i; }
            else if (s > v2) { v2 = s; i2 = i; }
        }
        out[b * 2 + 0] = (float)i1;
        out[b * 2 + 1] = (float)i2;
    }
}

extern "C" void kernel_launch(void* const* d_in, const int* in_sizes, int n_in,
                              void* d_out, int out_size, void* d_ws, size_t ws_size,
                              hipStream_t stream)
{
    (void)n_in; (void)out_size; (void)ws_size;
    const int*   input_ids  = (const int*)d_in[0];
    const int*   token_type = (const int*)d_in[1];
    const int*   attn_mask  = (const int*)d_in[2];
    const int*   location   = (const int*)d_in[3];
    const float* sense_emb  = (const float*)d_in[4];
    const float* word_emb   = (const float*)d_in[5];
    const float* pos_emb    = (const float*)d_in[6];
    const float* type_emb   = (const float*)d_in[7];
    const float* eg         = (const float*)d_in[8];
    const float* eb         = (const float*)d_in[9];
    const float* Wq         = (const float*)d_in[10];
    const float* bq         = (const float*)d_in[11];
    const float* Wk         = (const float*)d_in[12];
    const float* bk         = (const float*)d_in[13];
    const float* Wv         = (const float*)d_in[14];
    const float* bv         = (const float*)d_in[15];
    const float* Wo         = (const float*)d_in[16];
    const float* bo         = (const float*)d_in[17];
    const float* ln1g       = (const float*)d_in[18];
    const float* ln1b       = (const float*)d_in[19];
    const float* W1         = (const float*)d_in[20];
    const float* b1         = (const float*)d_in[21];
    const float* W2         = (const float*)d_in[22];
    const float* b2         = (const float*)d_in[23];
    const float* ln2g       = (const float*)d_in[24];
    const float* ln2b       = (const float*)d_in[25];
    const float* attWq      = (const float*)d_in[26];
    const float* attWk      = (const float*)d_in[27];
    float* out = (float*)d_out;

    int B = in_sizes[3];      // 32
    int S = in_sizes[0] / B;  // 256
    int NT = B * S;           // 8192
    size_t NTD = (size_t)NT * Dc;

    float*          x   = (float*)d_ws;
    unsigned short* xh  = (unsigned short*)(x + NTD);
    unsigned short* xl  = xh + NTD;
    float*          y   = (float*)(xl + NTD);
    float*          qkv = (float*)(y + NTD);
    unsigned short* aoh = (unsigned short*)(qkv + (size_t)NT * QS);
    unsigned short* aol = aoh + NTD;
    unsigned short* hh  = (unsigned short*)qkv;   // aliases qkv/ao (disjoint liveness)
    unsigned short* hl  = hh + (size_t)NT * FFc;
    float*          bc  = (float*)(aol + NTD);
    unsigned short* wqh = (unsigned short*)(bc + (size_t)Lc * QS);
    unsigned short* wql = wqh + (size_t)QS * Dc;
    unsigned short* woh = wql + (size_t)QS * Dc;
    unsigned short* wol = woh + (size_t)Dc * Dc;
    unsigned short* w1h = wol + (size_t)Dc * Dc;
    unsigned short* w1l = w1h + (size_t)FFc * Dc;
    unsigned short* w2h = w1l + (size_t)FFc * Dc;
    unsigned short* w2l = w2h + (size_t)Dc * FFc;
    float*          pq  = (float*)(w2l + (size_t)Dc * FFc);
    float*          sk  = pq + (size_t)B * ATTc;

    embed_kernel<<<NT, 256, 0, stream>>>(input_ids, token_type, word_emb,
                                         pos_emb, type_emb, eg, eb, x, xh, xl, S);
    biascat_kernel<<<Lc, 256, 0, stream>>>(bq, bk, bv, bc);

    dim3 gQKV(QS / 128, NT / 128);
    dim3 gD(Dc / 128, NT / 128);
    dim3 gF(FFc / 128, NT / 128);
    for (int l = 0; l < Lc; ++l) {
        convert_weights<<<1728, 256, 0, stream>>>(
            Wq + (size_t)l * Dc * Dc, Wk + (size_t)l * Dc * Dc,
            Wv + (size_t)l * Dc * Dc, Wo + (size_t)l * Dc * Dc,
            W1 + (size_t)l * Dc * FFc, W2 + (size_t)l * FFc * Dc,
            wqh, wql, woh, wol, w1h, w1l, w2h, w2l);
        mfma_gemm_split<0><<<gQKV, 256, 0, stream>>>(
            xh, xl, wqh, wql, bc + (size_t)l * QS, qkv, nullptr, nullptr, NT, QS, Dc);
        attn_mfma<<<B * Hc, 256, 0, stream>>>(qkv, attn_mask, aoh, aol, B, S);
        mfma_gemm_split<0><<<gD, 256, 0, stream>>>(
            aoh, aol, woh, wol, bo + (size_t)l * Dc, y, nullptr, nullptr, NT, Dc, Dc);
        resln_kernel<<<NT, 256, 0, stream>>>(x, y, ln1g + (size_t)l * Dc,
                                             ln1b + (size_t)l * Dc, xh, xl);
        mfma_gemm_split<1><<<gF, 256, 0, stream>>>(
            xh, xl, w1h, w1l, b1 + (size_t)l * FFc, nullptr, hh, hl, NT, FFc, Dc);
        mfma_gemm_split<0><<<gD, 256, 0, stream>>>(
            hh, hl, w2h, w2l, b2 + (size_t)l * Dc, y, nullptr, nullptr, NT, Dc, FFc);
        resln_kernel<<<NT, 256, 0, stream>>>(x, y, ln2g + (size_t)l * Dc,
                                             ln2b + (size_t)l * Dc, xh, xl);
    }

    pun_proj_kernel<<<B, 64, 0, stream>>>(x, location, attWq, pq, S);
    sense_proj_kernel<<<SENSEc, 64, 0, stream>>>(sense_emb, attWk, sk);
    top2_kernel<<<B, 64, 0, stream>>>(pq, sk, out);
}

// Round 5
// 6335.540 us; speedup vs baseline: 7.4182x; 1.0709x over previous
//
#include <hip/hip_runtime.h>
#include <math.h>

typedef __attribute__((ext_vector_type(8))) short short8;
typedef __attribute__((ext_vector_type(4))) float f32x4;

static constexpr int Lc = 12;
static constexpr int Hc = 12;
static constexpr int Dc = 768;
static constexpr int DHc = 64;
static constexpr int FFc = 3072;
static constexpr int SENSEc = 64;
static constexpr int ATTc = 64;
static constexpr int QS = 3 * Dc;   // 2304 packed q|k|v
static constexpr int KPAD = 72;     // LDS row stride (shorts) for V^T / P buffers

// fp32 -> bf16 RNE
__device__ __forceinline__ unsigned short f2bf(float f) {
    unsigned u = __float_as_uint(f);
    u = (u + 0x7FFFu + ((u >> 16) & 1u)) >> 16;
    return (unsigned short)u;
}
__device__ __forceinline__ float bf2f(unsigned short h) {
    return __uint_as_float((unsigned)h << 16);
}
__device__ __forceinline__ void splitbf(float v, unsigned short& h, unsigned short& l) {
    h = f2bf(v);
    l = f2bf(v - bf2f(h));
}

__device__ __forceinline__ void load_lds16(const void* g, void* l) {
    __builtin_amdgcn_global_load_lds(
        (const __attribute__((address_space(1))) unsigned int*)g,
        (__attribute__((address_space(3))) unsigned int*)l, 16, 0, 0);
}

// ---------------- block reduction (256 threads = 4 waves) ----------------
__device__ __forceinline__ float blockReduceSum256(float v, float* sred) {
#pragma unroll
    for (int off = 32; off > 0; off >>= 1) v += __shfl_down(v, off, 64);
    int lane = threadIdx.x & 63, wid = threadIdx.x >> 6;
    if (lane == 0) sred[wid] = v;
    __syncthreads();
    float total = sred[0] + sred[1] + sred[2] + sred[3];
    __syncthreads();
    return total;
}

// ---------------- embedding + LayerNorm -> x fp32 + split bf16 planes ------------
__global__ __launch_bounds__(256) void embed_kernel(
    const int* __restrict__ ids, const int* __restrict__ tts,
    const float* __restrict__ we, const float* __restrict__ pe,
    const float* __restrict__ te, const float* __restrict__ g,
    const float* __restrict__ b, float* __restrict__ x,
    unsigned short* __restrict__ xh, unsigned short* __restrict__ xl, int S)
{
    int tok = blockIdx.x, t = threadIdx.x;
    int ss = tok % S;
    int id = ids[tok], tt = tts[tok];
    __shared__ float sred[4];
    float v[3];
    float s = 0.f;
#pragma unroll
    for (int i = 0; i < 3; ++i) {
        int d = t + i * 256;
        v[i] = we[(size_t)id * Dc + d] + pe[(size_t)ss * Dc + d] + te[(size_t)tt * Dc + d];
        s += v[i];
    }
    float mu = blockReduceSum256(s, sred) * (1.f / Dc);
    float s2 = 0.f;
#pragma unroll
    for (int i = 0; i < 3; ++i) { v[i] -= mu; s2 += v[i] * v[i]; }
    float rstd = rsqrtf(blockReduceSum256(s2, sred) * (1.f / Dc) + 1e-12f);
    size_t ro = (size_t)tok * Dc;
#pragma unroll
    for (int i = 0; i < 3; ++i) {
        int d = t + i * 256;
        float val = v[i] * rstd * g[d] + b[d];
        x[ro + d] = val;
        unsigned short hb_, lb_;
        splitbf(val, hb_, lb_);
        xh[ro + d] = hb_;
        xl[ro + d] = lb_;
    }
}

// ---------------- residual + LayerNorm (in-place x) + split planes ----------------
__global__ __launch_bounds__(256) void resln_kernel(
    float* __restrict__ x, const float* __restrict__ y,
    const float* __restrict__ g, const float* __restrict__ b,
    unsigned short* __restrict__ xh, unsigned short* __restrict__ xl)
{
    int tok = blockIdx.x, t = threadIdx.x;
    __shared__ float sred[4];
    size_t ro = (size_t)tok * Dc;
    float v[3];
    float s = 0.f;
#pragma unroll
    for (int i = 0; i < 3; ++i) {
        int d = t + i * 256;
        v[i] = x[ro + d] + y[ro + d];
        s += v[i];
    }
    float mu = blockReduceSum256(s, sred) * (1.f / Dc);
    float s2 = 0.f;
#pragma unroll
    for (int i = 0; i < 3; ++i) { v[i] -= mu; s2 += v[i] * v[i]; }
    float rstd = rsqrtf(blockReduceSum256(s2, sred) * (1.f / Dc) + 1e-12f);
#pragma unroll
    for (int i = 0; i < 3; ++i) {
        int d = t + i * 256;
        float val = v[i] * rstd * g[d] + b[d];
        x[ro + d] = val;
        unsigned short hb_, lb_;
        splitbf(val, hb_, lb_);
        xh[ro + d] = hb_;
        xl[ro + d] = lb_;
    }
}

// ------------- weight convert+transpose fp32 [K,N] -> split bf16 [N,K] planes -----
__global__ __launch_bounds__(256) void convert_weights(
    const float* __restrict__ Wq, const float* __restrict__ Wk,
    const float* __restrict__ Wv, const float* __restrict__ Wo,
    const float* __restrict__ W1, const float* __restrict__ W2,
    unsigned short* __restrict__ qh, unsigned short* __restrict__ ql,
    unsigned short* __restrict__ oh, unsigned short* __restrict__ ol,
    unsigned short* __restrict__ h1, unsigned short* __restrict__ l1,
    unsigned short* __restrict__ h2, unsigned short* __restrict__ l2)
{
    int id = blockIdx.x;
    const float* src; unsigned short *dh, *dl; int Kd, Nd, tx, ty;
    if (id < 576) {
        int m = id / 144, tile = id % 144;
        src = (m == 0) ? Wq : (m == 1) ? Wk : (m == 2) ? Wv : Wo;
        if (m < 3) { dh = qh + (size_t)m * Dc * Dc; dl = ql + (size_t)m * Dc * Dc; }
        else       { dh = oh; dl = ol; }
        Kd = Dc; Nd = Dc; tx = tile % 12; ty = tile / 12;
    } else if (id < 1152) {
        int tile = id - 576;
        src = W1; dh = h1; dl = l1; Kd = Dc; Nd = FFc; tx = tile % 48; ty = tile / 48;
    } else {
        int tile = id - 1152;
        src = W2; dh = h2; dl = l2; Kd = FFc; Nd = Dc; tx = tile % 12; ty = tile / 12;
    }
    int k0 = ty * 64, n0 = tx * 64;
    __shared__ float tileS[64][65];
    int t = threadIdx.x, c = t & 63, r0 = t >> 6;
#pragma unroll
    for (int i = 0; i < 16; ++i) {
        int kr = r0 + i * 4;
        tileS[kr][c] = src[(size_t)(k0 + kr) * Nd + n0 + c];
    }
    __syncthreads();
#pragma unroll
    for (int i = 0; i < 16; ++i) {
        int nr = r0 + i * 4;
        float v = tileS[c][nr];
        unsigned short hb_, lb_;
        splitbf(v, hb_, lb_);
        size_t idx = (size_t)(n0 + nr) * Kd + k0 + c;
        dh[idx] = hb_;
        dl[idx] = lb_;
    }
}

// ---------------- packed qkv bias [L][2304] ----------------
__global__ __launch_bounds__(256) void biascat_kernel(
    const float* __restrict__ bq, const float* __restrict__ bk,
    const float* __restrict__ bv, float* __restrict__ out)
{
    int lyr = blockIdx.x, t = threadIdx.x;
    for (int j = t; j < QS; j += 256) {
        float v = (j < Dc) ? bq[lyr * Dc + j]
                : (j < 2 * Dc) ? bk[lyr * Dc + j - Dc]
                : bv[lyr * Dc + j - 2 * Dc];
        out[lyr * QS + j] = v;
    }
}

// ------------- split-bf16 MFMA GEMM: C = A @ Bt^T + bias -------------------------
// LDS planes use a 16B-chunk XOR swizzle: chunk c of row r stored at slot c^(r&7)
// (source-column permutation at staging; fragment reads XOR by row&7). Breaks the
// 128B-row-stride 16-way bank conflict down to free 2-way.
// MODE 0: fp32 out. MODE 1: GELU + split-bf16 out. MODE 2: single-bf16 out.
template <int MODE>
__global__ __launch_bounds__(256, 2) void mfma_gemm_split(
    const unsigned short* __restrict__ Ah, const unsigned short* __restrict__ Al,
    const unsigned short* __restrict__ Bh, const unsigned short* __restrict__ Bl,
    const float* __restrict__ bias, float* __restrict__ Cf,
    unsigned short* __restrict__ Ch, unsigned short* __restrict__ Cl,
    int M, int N, int K)
{
    __shared__ alignas(16) unsigned short Ash[128 * 64];
    __shared__ alignas(16) unsigned short Asl[128 * 64];
    __shared__ alignas(16) unsigned short Bsh[128 * 64];
    __shared__ alignas(16) unsigned short Bsl[128 * 64];
    int t = threadIdx.x, w = t >> 6, l = t & 63;
    int m0 = blockIdx.y * 128, n0 = blockIdx.x * 128;
    int wm = (w >> 1) * 64, wn = (w & 1) * 64;
    // swizzled source column: this lane's LDS slot (l&7) holds global chunk (l&7)^(row&7)
    int sw = (((l & 7) ^ (l >> 3)) << 3);
    size_t go = (size_t)(w * 8 + (l >> 3)) * K + sw;
    const unsigned short* gah = Ah + (size_t)m0 * K + go;
    const unsigned short* gal = Al + (size_t)m0 * K + go;
    const unsigned short* gbh = Bh + (size_t)n0 * K + go;
    const unsigned short* gbl = Bl + (size_t)n0 * K + go;
    int lo = w * 512 + l * 8;
    f32x4 acc[4][4];
#pragma unroll
    for (int i = 0; i < 4; ++i)
#pragma unroll
        for (int j = 0; j < 4; ++j) acc[i][j] = (f32x4)0.f;
    int fm = l & 15, grp = l >> 4;
    int axor = fm & 7;  // row&7 for fragment rows (wm/wn,i*16 are 0 mod 8)
    for (int k0 = 0; k0 < K; k0 += 64) {
        __syncthreads();
#pragma unroll
        for (int i = 0; i < 4; ++i) {
            size_t g = (size_t)(i * 32) * K + k0;
            int d = lo + i * 2048;
            load_lds16(gah + g, Ash + d);
            load_lds16(gal + g, Asl + d);
            load_lds16(gbh + g, Bsh + d);
            load_lds16(gbl + g, Bsl + d);
        }
        __syncthreads();
#pragma unroll
        for (int h = 0; h < 2; ++h) {
            int koff = (((h * 4 + grp) ^ axor) << 3);
            short8 fah[4], fal[4], fbh[4], fbl[4];
#pragma unroll
            for (int i = 0; i < 4; ++i) {
                int ra = (wm + i * 16 + fm) * 64 + koff;
                int rb = (wn + i * 16 + fm) * 64 + koff;
                fah[i] = *(const short8*)(Ash + ra);
                fal[i] = *(const short8*)(Asl + ra);
                fbh[i] = *(const short8*)(Bsh + rb);
                fbl[i] = *(const short8*)(Bsl + rb);
            }
#pragma unroll
            for (int i = 0; i < 4; ++i)
#pragma unroll
                for (int j = 0; j < 4; ++j) {
                    acc[i][j] = __builtin_amdgcn_mfma_f32_16x16x32_bf16(
                        fah[i], fbh[j], acc[i][j], 0, 0, 0);
                    acc[i][j] = __builtin_amdgcn_mfma_f32_16x16x32_bf16(
                        fah[i], fbl[j], acc[i][j], 0, 0, 0);
                    acc[i][j] = __builtin_amdgcn_mfma_f32_16x16x32_bf16(
                        fal[i], fbh[j], acc[i][j], 0, 0, 0);
                }
        }
    }
    int col_l = l & 15, row_l = (l >> 4) * 4;
#pragma unroll
    for (int j = 0; j < 4; ++j) {
        int col = n0 + wn + j * 16 + col_l;
        float bcv = bias[col];
#pragma unroll
        for (int i = 0; i < 4; ++i) {
            int row = m0 + wm + i * 16 + row_l;
#pragma unroll
            for (int r = 0; r < 4; ++r) {
                float v = acc[i][j][r] + bcv;
                size_t idx = (size_t)(row + r) * N + col;
                if (MODE == 1) {
                    v = 0.5f * v * (1.f + erff(v * 0.70710678118654752f));
                    unsigned short hb_, lb_;
                    splitbf(v, hb_, lb_);
                    Ch[idx] = hb_;
                    Cl[idx] = lb_;
                } else if (MODE == 2) {
                    Ch[idx] = f2bf(v);
                } else {
                    Cf[idx] = v;
                }
            }
        }
    }
}

// ------------- MFMA flash attention: one block per (b,head), 4 waves ------------
// qkv is bf16 [tok][2304] (q|k|v). K staged with the same XOR swizzle (row stride
// 64 shorts); V^T and P use KPAD=72 rows (2-way worst = free). fp32 softmax/O.
__global__ __launch_bounds__(256, 1) void attn_mfma(
    const unsigned short* __restrict__ qkv, const int* __restrict__ mask,
    unsigned short* __restrict__ aoh, unsigned short* __restrict__ aol,
    int B, int S)
{
    int bh = blockIdx.x, b = bh / Hc, hd = bh % Hc;
    int t = threadIdx.x, w = t >> 6, l = t & 63;
    int grp = l >> 4, lc = l & 15;
    __shared__ alignas(16) unsigned short Ks[256 * 64];       // [key][d] swizzled
    __shared__ alignas(16) unsigned short Vts[4][64 * KPAD];  // [chunk][d][key%64]
    __shared__ alignas(16) unsigned short Pw[4][64 * KPAD];   // [wave][q%64][key%64]
    __shared__ float mb[256];
    size_t rowbase = (size_t)(b * S) * QS;

    mb[t] = (1.f - (float)mask[b * S + t]) * -10000.0f;

    // ---- stage K (swizzled) and V^T panels (bf16 direct) ----
    for (int p = 0; p < 4; ++p) {
        int key = p * 64 + (t >> 2);
        int d0 = (t & 3) * 16;
        const unsigned short* ksrc = qkv + rowbase + (size_t)key * QS + Dc + hd * DHc + d0;
        short8 s0 = *(const short8*)ksrc;
        short8 s1 = *(const short8*)(ksrc + 8);
        int c0 = d0 >> 3;
        *(short8*)(Ks + key * 64 + (((c0 + 0) ^ (key & 7)) << 3)) = s0;
        *(short8*)(Ks + key * 64 + (((c0 + 1) ^ (key & 7)) << 3)) = s1;
        const unsigned short* vsrc = qkv + rowbase + (size_t)key * QS + 2 * Dc + hd * DHc + d0;
        short8 v0 = *(const short8*)vsrc;
        short8 v1 = *(const short8*)(vsrc + 8);
        int kk = t >> 2;
#pragma unroll
        for (int u = 0; u < 8; ++u) {
            Vts[p][(d0 + u) * KPAD + kk]     = (unsigned short)v0[u];
            Vts[p][(d0 + 8 + u) * KPAD + kk] = (unsigned short)v1[u];
        }
    }

    // ---- Q fragments direct from bf16 qkv (A-layout: m=lc, k=grp*8+j) ----
    int q0 = w * 64;
    short8 qf[4][2];
#pragma unroll
    for (int i = 0; i < 4; ++i)
#pragma unroll
        for (int kc = 0; kc < 2; ++kc)
            qf[i][kc] = *(const short8*)(qkv + rowbase
                        + (size_t)(q0 + 16 * i + lc) * QS + hd * DHc + kc * 32 + grp * 8);
    __syncthreads();

    f32x4 oacc[4][4];
#pragma unroll
    for (int i = 0; i < 4; ++i)
#pragma unroll
        for (int j = 0; j < 4; ++j) oacc[i][j] = (f32x4)0.f;
    float mstate[4][4], lstate[4][4];
#pragma unroll
    for (int i = 0; i < 4; ++i)
#pragma unroll
        for (int r = 0; r < 4; ++r) { mstate[i][r] = -3.0e38f; lstate[i][r] = 0.f; }

    for (int c = 0; c < 4; ++c) {
        f32x4 sacc[4][4];
#pragma unroll
        for (int i = 0; i < 4; ++i)
#pragma unroll
            for (int j = 0; j < 4; ++j) sacc[i][j] = (f32x4)0.f;
#pragma unroll
        for (int kc = 0; kc < 2; ++kc) {
            short8 kf[4];
#pragma unroll
            for (int j = 0; j < 4; ++j) {
                int krow = c * 64 + 16 * j + lc;
                kf[j] = *(const short8*)(Ks + krow * 64 + (((kc * 4 + grp) ^ (lc & 7)) << 3));
            }
#pragma unroll
            for (int i = 0; i < 4; ++i)
#pragma unroll
                for (int j = 0; j < 4; ++j)
                    sacc[i][j] = __builtin_amdgcn_mfma_f32_16x16x32_bf16(
                        qf[i][kc], kf[j], sacc[i][j], 0, 0, 0);
        }
#pragma unroll
        for (int j = 0; j < 4; ++j) {
            float mbv = mb[c * 64 + 16 * j + lc];
#pragma unroll
            for (int i = 0; i < 4; ++i)
#pragma unroll
                for (int r = 0; r < 4; ++r)
                    sacc[i][j][r] = sacc[i][j][r] * 0.125f + mbv;
        }
#pragma unroll
        for (int i = 0; i < 4; ++i)
#pragma unroll
            for (int r = 0; r < 4; ++r) {
                float cm = fmaxf(fmaxf(sacc[i][0][r], sacc[i][1][r]),
                                 fmaxf(sacc[i][2][r], sacc[i][3][r]));
#pragma unroll
                for (int mw = 1; mw < 16; mw <<= 1)
                    cm = fmaxf(cm, __shfl_xor(cm, mw, 16));
                float nm = fmaxf(mstate[i][r], cm);
                float alpha = expf(mstate[i][r] - nm);
                mstate[i][r] = nm;
                float rs = 0.f;
#pragma unroll
                for (int j = 0; j < 4; ++j) {
                    float p = expf(sacc[i][j][r] - nm);
                    sacc[i][j][r] = p;
                    rs += p;
                }
#pragma unroll
                for (int mw = 1; mw < 16; mw <<= 1)
                    rs += __shfl_xor(rs, mw, 16);
                lstate[i][r] = lstate[i][r] * alpha + rs;
#pragma unroll
                for (int j = 0; j < 4; ++j) oacc[i][j][r] *= alpha;
            }
#pragma unroll
        for (int i = 0; i < 4; ++i)
#pragma unroll
            for (int j = 0; j < 4; ++j)
#pragma unroll
                for (int r = 0; r < 4; ++r)
                    Pw[w][(16 * i + 4 * grp + r) * KPAD + 16 * j + lc] =
                        f2bf(sacc[i][j][r]);
        __syncthreads();
#pragma unroll
        for (int kc = 0; kc < 2; ++kc) {
            short8 pf[4], vf[4];
#pragma unroll
            for (int i = 0; i < 4; ++i)
                pf[i] = *(const short8*)(&Pw[w][(16 * i + lc) * KPAD + kc * 32 + grp * 8]);
#pragma unroll
            for (int j = 0; j < 4; ++j)
                vf[j] = *(const short8*)(&Vts[c][(16 * j + lc) * KPAD + kc * 32 + grp * 8]);
#pragma unroll
            for (int i = 0; i < 4; ++i)
#pragma unroll
                for (int j = 0; j < 4; ++j)
                    oacc[i][j] = __builtin_amdgcn_mfma_f32_16x16x32_bf16(
                        pf[i], vf[j], oacc[i][j], 0, 0, 0);
        }
        __syncthreads();
    }
#pragma unroll
    for (int i = 0; i < 4; ++i)
#pragma unroll
        for (int r = 0; r < 4; ++r) {
            float inv = 1.f / lstate[i][r];
            size_t tok = (size_t)(b * S + q0 + 16 * i + 4 * grp + r);
#pragma unroll
            for (int j = 0; j < 4; ++j) {
                float v = oacc[i][j][r] * inv;
                size_t idx = tok * Dc + hd * DHc + 16 * j + lc;
                unsigned short hb_, lb_;
                splitbf(v, hb_, lb_);
                aoh[idx] = hb_;
                aol[idx] = lb_;
            }
        }
}

// ---------------- final head (fp32 from fp32 master) ----------------
__global__ __launch_bounds__(64) void pun_proj_kernel(
    const float* __restrict__ x, const int* __restrict__ loc,
    const float* __restrict__ Wq, float* __restrict__ pq, int S)
{
    __shared__ float pun[Dc];
    int b = blockIdx.x, t = threadIdx.x;
    const float* row = x + ((size_t)b * S + loc[b]) * Dc;
    for (int i = t; i < Dc; i += 64) pun[i] = row[i];
    __syncthreads();
    float acc = 0.f;
    for (int d = 0; d < Dc; ++d) acc += pun[d] * Wq[(size_t)d * ATTc + t];
    pq[b * ATTc + t] = acc;
}

__global__ __launch_bounds__(64) void sense_proj_kernel(
    const float* __restrict__ se, const float* __restrict__ Wk,
    float* __restrict__ sk)
{
    __shared__ float srow[Dc];
    int i = blockIdx.x, t = threadIdx.x;
    const float* row = se + (size_t)i * Dc;
    for (int j = t; j < Dc; j += 64) srow[j] = row[j];
    __syncthreads();
    float acc = 0.f;
    for (int d = 0; d < Dc; ++d) acc += srow[d] * Wk[(size_t)d * ATTc + t];
    sk[i * ATTc + t] = acc;
}

__global__ __launch_bounds__(64) void top2_kernel(
    const float* __restrict__ pq, const float* __restrict__ sk,
    float* __restrict__ out)
{
    __shared__ float pqs[ATTc];
    __shared__ float scs[SENSEc];
    int b = blockIdx.x, t = threadIdx.x;
    pqs[t] = pq[b * ATTc + t];
    __syncthreads();
    float acc = 0.f;
#pragma unroll
    for (int d = 0; d < ATTc; ++d) acc += pqs[d] * sk[t * ATTc + d];
    scs[t] = acc;
    __syncthreads();
    if (t == 0) {
        float v1 = -INFINITY, v2 = -INFINITY;
        int i1 = 0, i2 = 0;
        for (int i = 0; i < SENSEc; ++i) {
            float s = scs[i];
            if (s > v1) { v2 = v1; i2 = i1; v1 = s; i1 = i; }
            else if (s > v2) { v2 = s; i2 = i; }
        }
        out[b * 2 + 0] = (float)i1;
        out[b * 2 + 1] = (float)i2;
    }
}

extern "C" void kernel_launch(void* const* d_in, const int* in_sizes, int n_in,
                              void* d_out, int out_size, void* d_ws, size_t ws_size,
                              hipStream_t stream)
{
    (void)n_in; (void)out_size; (void)ws_size;
    const int*   input_ids  = (const int*)d_in[0];
    const int*   token_type = (const int*)d_in[1];
    const int*   attn_mask  = (const int*)d_in[2];
    const int*   location   = (const int*)d_in[3];
    const float* sense_emb  = (const float*)d_in[4];
    const float* word_emb   = (const float*)d_in[5];
    const float* pos_emb    = (const float*)d_in[6];
    const float* type_emb   = (const float*)d_in[7];
    const float* eg         = (const float*)d_in[8];
    const float* eb         = (const float*)d_in[9];
    const float* Wq         = (const float*)d_in[10];
    const float* bq         = (const float*)d_in[11];
    const float* Wk         = (const float*)d_in[12];
    const float* bk         = (const float*)d_in[13];
    const float* Wv         = (const float*)d_in[14];
    const float* bv         = (const float*)d_in[15];
    const float* Wo         = (const float*)d_in[16];
    const float* bo         = (const float*)d_in[17];
    const float* ln1g       = (const float*)d_in[18];
    const float* ln1b       = (const float*)d_in[19];
    const float* W1         = (const float*)d_in[20];
    const float* b1         = (const float*)d_in[21];
    const float* W2         = (const float*)d_in[22];
    const float* b2         = (const float*)d_in[23];
    const float* ln2g       = (const float*)d_in[24];
    const float* ln2b       = (const float*)d_in[25];
    const float* attWq      = (const float*)d_in[26];
    const float* attWk      = (const float*)d_in[27];
    float* out = (float*)d_out;

    int B = in_sizes[3];      // 32
    int S = in_sizes[0] / B;  // 256
    int NT = B * S;           // 8192
    size_t NTD = (size_t)NT * Dc;

    float*          x   = (float*)d_ws;
    unsigned short* xh  = (unsigned short*)(x + NTD);
    unsigned short* xl  = xh + NTD;
    float*          y   = (float*)(xl + NTD);
    // scratch union (sized by hh/hl = 100.7 MB): {qkv bf16 + aoh/aol} <-> {hh/hl}
    unsigned short* hh  = (unsigned short*)(y + NTD);   // [NT,FF]
    unsigned short* hl  = hh + (size_t)NT * FFc;        // [NT,FF]
    unsigned short* qkv = hh;                           // [NT,2304] bf16 (aliases hh/hl)
    unsigned short* aoh = qkv + (size_t)NT * QS;        // [NT,D]
    unsigned short* aol = aoh + NTD;                    // [NT,D]
    float*          bc  = (float*)(hl + (size_t)NT * FFc);  // [L,2304]
    unsigned short* wqh = (unsigned short*)(bc + (size_t)Lc * QS);
    unsigned short* wql = wqh + (size_t)QS * Dc;
    unsigned short* woh = wql + (size_t)QS * Dc;
    unsigned short* wol = woh + (size_t)Dc * Dc;
    unsigned short* w1h = wol + (size_t)Dc * Dc;
    unsigned short* w1l = w1h + (size_t)FFc * Dc;
    unsigned short* w2h = w1l + (size_t)FFc * Dc;
    unsigned short* w2l = w2h + (size_t)Dc * FFc;
    float*          pq  = (float*)(w2l + (size_t)Dc * FFc);
    float*          sk  = pq + (size_t)B * ATTc;

    embed_kernel<<<NT, 256, 0, stream>>>(input_ids, token_type, word_emb,
                                         pos_emb, type_emb, eg, eb, x, xh, xl, S);
    biascat_kernel<<<Lc, 256, 0, stream>>>(bq, bk, bv, bc);

    dim3 gQKV(QS / 128, NT / 128);
    dim3 gD(Dc / 128, NT / 128);
    dim3 gF(FFc / 128, NT / 128);
    for (int l = 0; l < Lc; ++l) {
        convert_weights<<<1728, 256, 0, stream>>>(
            Wq + (size_t)l * Dc * Dc, Wk + (size_t)l * Dc * Dc,
            Wv + (size_t)l * Dc * Dc, Wo + (size_t)l * Dc * Dc,
            W1 + (size_t)l * Dc * FFc, W2 + (size_t)l * FFc * Dc,
            wqh, wql, woh, wol, w1h, w1l, w2h, w2l);
        mfma_gemm_split<2><<<gQKV, 256, 0, stream>>>(
            xh, xl, wqh, wql, bc + (size_t)l * QS, nullptr, qkv, nullptr, NT, QS, Dc);
        attn_mfma<<<B * Hc, 256, 0, stream>>>(qkv, attn_mask, aoh, aol, B, S);
        mfma_gemm_split<0><<<gD, 256, 0, stream>>>(
            aoh, aol, woh, wol, bo + (size_t)l * Dc, y, nullptr, nullptr, NT, Dc, Dc);
        resln_kernel<<<NT, 256, 0, stream>>>(x, y, ln1g + (size_t)l * Dc,
                                             ln1b + (size_t)l * Dc, xh, xl);
        mfma_gemm_split<1><<<gF, 256, 0, stream>>>(
            xh, xl, w1h, w1l, b1 + (size_t)l * FFc, nullptr, hh, hl, NT, FFc, Dc);
        mfma_gemm_split<0><<<gD, 256, 0, stream>>>(
            hh, hl, w2h, w2l, b2 + (size_t)l * Dc, y, nullptr, nullptr, NT, Dc, FFc);
        resln_kernel<<<NT, 256, 0, stream>>>(x, y, ln2g + (size_t)l * Dc,
                                             ln2b + (size_t)l * Dc, xh, xl);
    }

    pun_proj_kernel<<<B, 64, 0, stream>>>(x, location, attWq, pq, S);
    sense_proj_kernel<<<SENSEc, 64, 0, stream>>>(sense_emb, attWk, sk);
    top2_kernel<<<B, 64, 0, stream>>>(pq, sk, out);
}